// Round 1
// baseline (120.013 us; speedup 1.0000x reference)
//
#include <hip/hip_runtime.h>

// Depthwise Gaussian blur, K=121, replicate pad -> SEPARABLE: two 1D passes.
// x: (8,3,512,512) fp32, sigma scalar fp32. out fp32 same shape.

#define HH    512
#define WW    512
#define NIMG  24          // 8*3 independent planes
#define RAD   60
#define KTAPS 128         // 121 real taps + 7 zero taps (unroll-by-8 friendly)

// ---------------- weights: normalized 1D gaussian, zero-padded to 128 -------
__global__ void gauss_weights(const float* __restrict__ sigma,
                              float* __restrict__ wgt) {
    const int i = threadIdx.x;            // 128 threads
    const float s = sigma[0] * 8.0f + 16.0f;
    const float inv2v = 1.0f / (2.0f * s * s);
    float g = 0.0f;
    if (i < 121) {
        const float c = (float)i - 60.0f;
        g = expf(-(c * c) * inv2v);
    }
    __shared__ float red[128];
    red[i] = g;
    __syncthreads();
    for (int off = 64; off > 0; off >>= 1) {
        if (i < off) red[i] += red[i + off];
        __syncthreads();
    }
    wgt[i] = g / red[0];                  // i>=121 -> exactly 0
}

// ---------------- vertical pass ---------------------------------------------
// Tile: 256 output rows x 32 cols. LDS holds 384 input rows x 32 cols (48 KB).
// Thread = (tx 0..7: float4 col group) x (ty 0..31: 8 consecutive output rows).
// Sliding 8-row register window, ping-pong buffers -> no rotation movs.
#define V_TW     32
#define V_TH     256
#define V_INROWS 384

#define INNER8(CUR, NXT, KO)                                              \
    _Pragma("unroll")                                                     \
    for (int ki = 0; ki < 8; ++ki) {                                      \
        NXT[ki] = sm4[(r0 + ((KO) + 1) * 8 + ki) * 8 + tx];               \
        const float wk = wgt[(KO) * 8 + ki];                              \
        _Pragma("unroll")                                                 \
        for (int j = 0; j < 8; ++j) {                                     \
            const int idx = ki + j;                                       \
            const float4 v = (idx < 8) ? CUR[idx] : NXT[idx - 8];         \
            acc[j].x += wk * v.x; acc[j].y += wk * v.y;                   \
            acc[j].z += wk * v.z; acc[j].w += wk * v.w;                   \
        }                                                                 \
    }

__global__ __launch_bounds__(256, 3) void blur_v(
        const float* __restrict__ x, const float* __restrict__ wgt,
        float* __restrict__ tmp) {
    __shared__ float sm[V_INROWS * V_TW];            // 48 KB -> 3 blocks/CU
    const int tid = threadIdx.x;
    const int w0  = blockIdx.x * V_TW;
    const int h0  = blockIdx.y * V_TH;
    const float* __restrict__ src = x + (size_t)blockIdx.z * (HH * WW);

    // load 384 rows x 32 cols, one float4 per thread per iter (coalesced 128B/row)
    {
        const int fc = (tid & 7) * 4;
        int r = tid >> 3;                            // 0..31
        #pragma unroll
        for (int it = 0; it < 12; ++it, r += 32) {
            int gr = h0 - RAD + r;
            gr = gr < 0 ? 0 : (gr > HH - 1 ? HH - 1 : gr);
            *(float4*)&sm[r * V_TW + fc] =
                *(const float4*)&src[(size_t)gr * WW + w0 + fc];
        }
    }
    __syncthreads();

    const int tx = tid & 7;
    const int r0 = (tid >> 3) * 8;                   // first output row (local)
    const float4* __restrict__ sm4 = (const float4*)sm;   // row stride = 8 float4

    float4 acc[8];
    #pragma unroll
    for (int j = 0; j < 8; ++j) acc[j] = make_float4(0.f, 0.f, 0.f, 0.f);

    float4 wa[8], wb[8];
    #pragma unroll
    for (int m = 0; m < 8; ++m) wa[m] = sm4[(r0 + m) * 8 + tx];

    #pragma unroll 1
    for (int ko = 0; ko < 16; ko += 2) {             // 128 taps, ping-pong
        INNER8(wa, wb, ko)
        INNER8(wb, wa, ko + 1)
    }

    float* __restrict__ dst = tmp + (size_t)blockIdx.z * (HH * WW);
    #pragma unroll
    for (int j = 0; j < 8; ++j)
        *(float4*)&dst[(size_t)(h0 + r0 + j) * WW + w0 + tx * 4] = acc[j];
}

// ---------------- horizontal pass -------------------------------------------
// Tile: 4 rows x full 512-wide row. 640 input cols (halo, clamped) stored in
// LDS padded as 8 floats + 1 pad-float4 per group (48B) so the stride-32B
// float4 compute reads cover all 32 banks. Each lane computes 8 consecutive
// output cols (two float4 accumulators).
#define HP_ROW 960   // 80 groups * 12 floats

__global__ __launch_bounds__(256, 4) void blur_h(
        const float* __restrict__ tmp, const float* __restrict__ wgt,
        float* __restrict__ out) {
    __shared__ float sm[4 * HP_ROW];                 // 15 KB
    const int tid = threadIdx.x;
    const int h0  = blockIdx.x * 4;
    const float* __restrict__ src = tmp + (size_t)blockIdx.y * (HH * WW);

    for (int c = tid; c < 640; c += 256) {
        int gc = c - RAD;
        gc = gc < 0 ? 0 : (gc > WW - 1 ? WW - 1 : gc);
        const int la = ((c >> 3) * 12) + (c & 7);
        #pragma unroll
        for (int r = 0; r < 4; ++r)
            sm[r * HP_ROW + la] = src[(size_t)(h0 + r) * WW + gc];
    }
    __syncthreads();

    const int row  = tid >> 6;                       // 0..3 (wave-uniform)
    const int lane = tid & 63;                       // output cols lane*8..+7
    const float* __restrict__ bs = sm + row * HP_ROW + lane * 12;

    float accA[4] = {0.f, 0.f, 0.f, 0.f};
    float accB[4] = {0.f, 0.f, 0.f, 0.f};
    #pragma unroll
    for (int s = 0; s < 34; ++s) {
        const float4 v = *(const float4*)(bs + (s >> 1) * 12 + (s & 1) * 4);
        const float va[4] = {v.x, v.y, v.z, v.w};
        #pragma unroll
        for (int cc = 0; cc < 4; ++cc) {
            const int p = 4 * s + cc;                // window index
            #pragma unroll
            for (int j = 0; j < 8; ++j) {
                const int k = p - j;                 // tap index
                if (k >= 0 && k < KTAPS) {
                    const float wk = wgt[k];
                    if (j < 4) accA[j]     += wk * va[cc];
                    else       accB[j - 4] += wk * va[cc];
                }
            }
        }
    }

    float* __restrict__ dst = out + (size_t)blockIdx.y * (HH * WW)
                                  + (size_t)(h0 + row) * WW + lane * 8;
    *(float4*)dst       = make_float4(accA[0], accA[1], accA[2], accA[3]);
    *(float4*)(dst + 4) = make_float4(accB[0], accB[1], accB[2], accB[3]);
}

// ---------------- launch -----------------------------------------------------
extern "C" void kernel_launch(void* const* d_in, const int* in_sizes, int n_in,
                              void* d_out, int out_size, void* d_ws, size_t ws_size,
                              hipStream_t stream) {
    const float* x     = (const float*)d_in[0];
    const float* sigma = (const float*)d_in[1];
    float* out = (float*)d_out;

    float* wgt = (float*)d_ws;                       // 128 floats
    float* tmp = (float*)d_ws + 512;                 // 24*512*512 floats (~25.2 MB)

    gauss_weights<<<dim3(1), dim3(128), 0, stream>>>(sigma, wgt);
    blur_v<<<dim3(WW / V_TW, HH / V_TH, NIMG), dim3(256), 0, stream>>>(x, wgt, tmp);
    blur_h<<<dim3(HH / 4, NIMG), dim3(256), 0, stream>>>(tmp, wgt, out);
}